// Round 7
// baseline (23518.887 us; speedup 1.0000x reference)
//
#include <hip/hip_runtime.h>

#define TT 512
#define BB 64
#define II 128
#define HH 1024
#define OO 128
#define NWG 196

typedef _Float16 half8 __attribute__((ext_vector_type(8)));
typedef float floatx4 __attribute__((ext_vector_type(4)));
typedef unsigned long long u64;

__device__ unsigned g_bar_cnt;   // reset by prep_x each call (agent-scope store)

__device__ __forceinline__ float sigm(float x){ return 1.0f/(1.0f + __expf(-x)); }

union H8cv { u64 u[2]; half8 h; };

// agent-scope (cross-XCD coherent, LLC-direct) h-fragment load
__device__ __forceinline__ half8 ld_h8_dev(const _Float16* p){
  H8cv cv;
  cv.u[0] = __hip_atomic_load((const u64*)p + 0, __ATOMIC_RELAXED, __HIP_MEMORY_SCOPE_AGENT);
  cv.u[1] = __hip_atomic_load((const u64*)p + 1, __ATOMIC_RELAXED, __HIP_MEMORY_SCOPE_AGENT);
  return cv.h;
}

// Pack adjacent-column pair into one 32-bit agent-scope store (even lane stores).
// Lanes n and n^1 hold adjacent columns of the same row.
__device__ __forceinline__ void st_h_pair(_Float16* rowbase, int col, float v, int lane){
  unsigned mv = (unsigned)__builtin_bit_cast(unsigned short, (_Float16)v);
  unsigned pv = ((unsigned)__shfl_xor((int)mv, 1, 64)) & 0xffffu;
  if (!(lane & 1)){
    unsigned word = (pv << 16) | mv;
    __hip_atomic_store((unsigned*)(rowbase + col), word,
                       __ATOMIC_RELAXED, __HIP_MEMORY_SCOPE_AGENT);
  }
}

// Monotonic grid barrier (no L2 invalidate: weights stay L2-resident).
// Producer: drain vmem, syncthreads, thread0 RELEASE fetch_add (buffer_wbl2 sc1
// writeback of dirty lines to LLC, no invalidate of clean lines). Consumer:
// relaxed spin; h reads are agent-scope (LLC-direct) so no acquire-invalidate.
__device__ __forceinline__ void fastbar(unsigned target){
  asm volatile("s_waitcnt vmcnt(0)" ::: "memory");
  __syncthreads();
  if (threadIdx.x == 0){
    __hip_atomic_fetch_add(&g_bar_cnt, 1u, __ATOMIC_RELEASE, __HIP_MEMORY_SCOPE_AGENT);
    while (__hip_atomic_load(&g_bar_cnt, __ATOMIC_RELAXED, __HIP_MEMORY_SCOPE_AGENT) < target)
      __builtin_amdgcn_s_sleep(2);
  }
  __syncthreads();
}

// ---------------- prep kernels ----------------
__global__ void prep_x_kernel(const float* __restrict__ x, _Float16* __restrict__ X16){
  if (blockIdx.x == 0 && threadIdx.x == 0)
    __hip_atomic_store(&g_bar_cnt, 0u, __ATOMIC_RELAXED, __HIP_MEMORY_SCOPE_AGENT);
  int idx = blockIdx.x*256 + threadIdx.x;         // idx over [t][b][i]
  int i = idx & (II-1);
  int b = (idx >> 7) & (BB-1);
  int t = idx >> 13;
  X16[idx] = (_Float16)x[((size_t)b*TT + t)*II + i];
}

__global__ void prep_w_kernel(const float* __restrict__ wih1, const float* __restrict__ whh1,
                              const float* __restrict__ wih2, const float* __restrict__ whh2,
                              const float* __restrict__ wlin,
                              _Float16* __restrict__ W1, _Float16* __restrict__ W2,
                              _Float16* __restrict__ WL, _Float16* __restrict__ H1,
                              _Float16* __restrict__ H2){
  long idx = (long)blockIdx.x*256 + threadIdx.x;
  const long n1 = 4096L*1152, n2 = 4096L*2048, nl = 128L*1024;
  if (idx < n1){
    int k = (int)(idx % 1152); int j = (int)(idx / 1152);
    W1[idx] = (_Float16)(k < II ? wih1[(size_t)j*II + k] : whh1[(size_t)j*HH + (k-II)]);
  } else if ((idx -= n1) < n2){
    int k = (int)(idx % 2048); int j = (int)(idx / 2048);
    W2[idx] = (_Float16)(k < HH ? wih2[(size_t)j*HH + k] : whh2[(size_t)j*HH + (k-HH)]);
  } else if ((idx -= n2) < nl){
    WL[idx] = (_Float16)wlin[idx];
  } else {
    idx -= nl;                                    // [0, 2*BB*HH)
    H1[idx] = (_Float16)0.0f;
    H2[idx] = (_Float16)0.0f;
  }
}

// ---------------- persistent pipelined LSTM (NORMAL launch) ----------------
// 196 WGs x 256 thr, plain <<<>>> launch — hipLaunchCooperativeKernel is the
// prime suspect for the R2/3/5 silent launch failures, so it is removed.
// 196 blocks of 256 thr on 256 CUs, breadth-first dispatch -> co-resident.
//   wg   0..63 : layer-1, 16 units (64x64 gate tile, K=1152)
//   wg  64..191: layer-2,  8 units (64x32 gate tile, K=2048)
//   wg 192..195: output projection, 32 cols (64x32, K=1024)
// Interval s: L1 t=s, L2 t=s-1, Y t=s-2; fastbar between intervals.
__global__ void __launch_bounds__(256, 1)
lstm_persist_kernel(const _Float16* __restrict__ X16,
                    const _Float16* __restrict__ W1,
                    const _Float16* __restrict__ W2,
                    const _Float16* __restrict__ WL,
                    _Float16* __restrict__ H1,
                    _Float16* __restrict__ H2,
                    const float* __restrict__ bi1, const float* __restrict__ bh1,
                    const float* __restrict__ bi2, const float* __restrict__ bh2,
                    const float* __restrict__ blin,
                    float* __restrict__ out)
{
  const int wg   = blockIdx.x;
  const int tid  = threadIdx.x;
  const int wv   = tid >> 6;
  const int lane = tid & 63;
  const int q    = lane >> 4;
  const int n    = lane & 15;
  const int mrow = wv << 4;
  const floatx4 zero4 = {0.f, 0.f, 0.f, 0.f};

  if (wg < 64){
    // ---------------- layer 1 ----------------
    const int j0 = wg << 4;
    const int j  = j0 + n;
    const _Float16* wrow[4];
    float bias[4];
#pragma unroll
    for (int g = 0; g < 4; ++g){
      wrow[g] = W1 + (size_t)(g*HH + j)*1152 + q*8;
      bias[g] = bi1[g*HH + j] + bh1[g*HH + j];
    }
    // x-part weights: registers for all 512 steps
    half8 Wx[4][4];
#pragma unroll
    for (int g = 0; g < 4; ++g)
#pragma unroll
      for (int c = 0; c < 4; ++c)
        Wx[g][c] = *(const half8*)(wrow[g] + c*32);

    float c1s[4] = {0.f, 0.f, 0.f, 0.f};
    for (int s = 0; s < TT + 2; ++s){
      if (s < TT){
        const int t = s;
        const _Float16* xb = X16 + ((size_t)t*BB + (mrow+n))*II + q*8;
        const _Float16* hb = H1 + ((size_t)((t+1)&1)*BB + (mrow+n))*HH + q*8;
        half8 xf[4];
#pragma unroll
        for (int c = 0; c < 4; ++c) xf[c] = *(const half8*)(xb + c*32);
        half8 hA[32];
#pragma unroll
        for (int c = 0; c < 32; ++c) hA[c] = ld_h8_dev(hb + c*32);

        floatx4 acc[4];
#pragma unroll
        for (int g = 0; g < 4; ++g) acc[g] = zero4;
#pragma unroll
        for (int c = 0; c < 4; ++c)
#pragma unroll
          for (int g = 0; g < 4; ++g)
            acc[g] = __builtin_amdgcn_mfma_f32_16x16x32_f16(xf[c], Wx[g][c], acc[g], 0, 0, 0);
#pragma unroll
        for (int g = 0; g < 4; ++g){
          half8 Wb[32];
#pragma unroll
          for (int c = 0; c < 32; ++c) Wb[c] = *(const half8*)(wrow[g] + (4+c)*32);
#pragma unroll
          for (int c = 0; c < 32; ++c)
            acc[g] = __builtin_amdgcn_mfma_f32_16x16x32_f16(hA[c], Wb[c], acc[g], 0, 0, 0);
        }
        _Float16* ho = H1 + (size_t)(t&1)*BB*HH;
#pragma unroll
        for (int r = 0; r < 4; ++r){
          float gi = acc[0][r] + bias[0];
          float gf = acc[1][r] + bias[1];
          float gg = acc[2][r] + bias[2];
          float go = acc[3][r] + bias[3];
          float cc = sigm(gf)*c1s[r] + sigm(gi)*tanhf(gg);
          c1s[r] = cc;
          float h = sigm(go)*tanhf(cc);
          st_h_pair(ho + (size_t)(mrow + q*4 + r)*HH, j, h, lane);
        }
      }
      fastbar(NWG*(unsigned)(s+1));
    }
  } else if (wg < 192){
    // ---------------- layer 2 ----------------
    const int j0 = (wg - 64) << 3;
    const int jj = j0 + (n & 7);
    const _Float16* wrow[2];
#pragma unroll
    for (int p = 0; p < 2; ++p)
      wrow[p] = W2 + (size_t)((p*2 + (n>>3))*HH + jj)*2048 + q*8;
    float bias[4];
#pragma unroll
    for (int g = 0; g < 4; ++g) bias[g] = bi2[g*HH + jj] + bh2[g*HH + jj];
    float c2s[2] = {0.f, 0.f};
    const int rbase = (n < 8) ? 0 : 2;
    for (int s = 0; s < TT + 2; ++s){
      if (s >= 1 && s <= TT){
        const int t = s - 1;
        const _Float16* a1 = H1 + ((size_t)(t&1)*BB + (mrow+n))*HH + q*8;
        const _Float16* a2 = H2 + ((size_t)((t+1)&1)*BB + (mrow+n))*HH + q*8;
        half8 hA1[32];
#pragma unroll
        for (int c = 0; c < 32; ++c) hA1[c] = ld_h8_dev(a1 + c*32);
        half8 hA2[32];
#pragma unroll
        for (int c = 0; c < 32; ++c) hA2[c] = ld_h8_dev(a2 + c*32);

        floatx4 acc[2];
        acc[0] = zero4; acc[1] = zero4;
#pragma unroll
        for (int p = 0; p < 2; ++p){
          half8 Wb[32];
#pragma unroll
          for (int c = 0; c < 32; ++c) Wb[c] = *(const half8*)(wrow[p] + c*32);
#pragma unroll
          for (int c = 0; c < 32; ++c)
            acc[p] = __builtin_amdgcn_mfma_f32_16x16x32_f16(hA1[c], Wb[c], acc[p], 0, 0, 0);
#pragma unroll
          for (int c = 0; c < 32; ++c) Wb[c] = *(const half8*)(wrow[p] + (32+c)*32);
#pragma unroll
          for (int c = 0; c < 32; ++c)
            acc[p] = __builtin_amdgcn_mfma_f32_16x16x32_f16(hA2[c], Wb[c], acc[p], 0, 0, 0);
        }
        float vi[4], vf[4], vg[4], vo[4];
#pragma unroll
        for (int r = 0; r < 4; ++r){
          float p0 = acc[0][r], p1 = acc[1][r];
          float s0 = __shfl_xor(p0, 8, 64);
          float s1 = __shfl_xor(p1, 8, 64);
          vi[r] = (n < 8) ? p0 : s0;
          vf[r] = (n < 8) ? s0 : p0;
          vg[r] = (n < 8) ? p1 : s1;
          vo[r] = (n < 8) ? s1 : p1;
        }
        _Float16* ho = H2 + (size_t)(t&1)*BB*HH;
#pragma unroll
        for (int rr = 0; rr < 2; ++rr){
          int r = rbase + rr;
          float gi = vi[r] + bias[0];
          float gf = vf[r] + bias[1];
          float gg = vg[r] + bias[2];
          float go = vo[r] + bias[3];
          float cc = sigm(gf)*c2s[rr] + sigm(gi)*tanhf(gg);
          c2s[rr] = cc;
          float h = sigm(go)*tanhf(cc);
          st_h_pair(ho + (size_t)(mrow + q*4 + r)*HH, jj, h, lane);
        }
      }
      fastbar(NWG*(unsigned)(s+1));
    }
  } else {
    // ---------------- output projection ----------------
    const int j0 = (wg - 192) << 5;
    const _Float16* wrow[2];
    float by[2];
#pragma unroll
    for (int p = 0; p < 2; ++p){
      wrow[p] = WL + (size_t)(j0 + p*16 + n)*HH + q*8;
      by[p] = blin[j0 + p*16 + n];
    }
    for (int s = 0; s < TT + 2; ++s){
      if (s >= 2){
        const int t = s - 2;
        const _Float16* a2 = H2 + ((size_t)(t&1)*BB + (mrow+n))*HH + q*8;
        half8 hA[32];
#pragma unroll
        for (int c = 0; c < 32; ++c) hA[c] = ld_h8_dev(a2 + c*32);
        floatx4 acc[2];
        acc[0] = zero4; acc[1] = zero4;
#pragma unroll
        for (int p = 0; p < 2; ++p){
          half8 Wb[32];
#pragma unroll
          for (int c = 0; c < 32; ++c) Wb[c] = *(const half8*)(wrow[p] + c*32);
#pragma unroll
          for (int c = 0; c < 32; ++c)
            acc[p] = __builtin_amdgcn_mfma_f32_16x16x32_f16(hA[c], Wb[c], acc[p], 0, 0, 0);
        }
#pragma unroll
        for (int p = 0; p < 2; ++p){
          int col = j0 + p*16 + n;
#pragma unroll
          for (int r = 0; r < 4; ++r){
            int b = mrow + q*4 + r;
            out[((size_t)b*TT + t)*OO + col] = acc[p][r] + by[p];
          }
        }
      }
      fastbar(NWG*(unsigned)(s+1));
    }
  }
}

// ---------------- launch ----------------
extern "C" void kernel_launch(void* const* d_in, const int* in_sizes, int n_in,
                              void* d_out, int out_size, void* d_ws, size_t ws_size,
                              hipStream_t stream){
  const float* x    = (const float*)d_in[0];
  const float* wih1 = (const float*)d_in[1];
  const float* whh1 = (const float*)d_in[2];
  const float* bi1  = (const float*)d_in[3];
  const float* bh1  = (const float*)d_in[4];
  const float* wih2 = (const float*)d_in[5];
  const float* whh2 = (const float*)d_in[6];
  const float* bi2  = (const float*)d_in[7];
  const float* bh2  = (const float*)d_in[8];
  const float* wlin = (const float*)d_in[9];
  const float* blin = (const float*)d_in[10];
  float* out = (float*)d_out;

  char* ws = (char*)d_ws;
  _Float16* X16 = (_Float16*)(ws + 0);          //  8,388,608  [512][64][128]
  _Float16* W1  = (_Float16*)(ws + 8388608);    //  9,437,184  [4096][1152]
  _Float16* W2  = (_Float16*)(ws + 17825792);   // 16,777,216  [4096][2048]
  _Float16* WL  = (_Float16*)(ws + 34603008);   //    262,144  [128][1024]
  _Float16* H1  = (_Float16*)(ws + 34865152);   //    262,144  [2][64][1024]
  _Float16* H2  = (_Float16*)(ws + 35127296);   //    262,144  [2][64][1024]

  prep_x_kernel<<<dim3(16384), dim3(256), 0, stream>>>(x, X16);
  prep_w_kernel<<<dim3(52224), dim3(256), 0, stream>>>(wih1, whh1, wih2, whh2, wlin,
                                                       W1, W2, WL, H1, H2);

  lstm_persist_kernel<<<dim3(NWG), dim3(256), 0, stream>>>(
      X16, W1, W2, WL, H1, H2, bi1, bh1, bi2, bh2, blin, out);
}

// Round 8
// 21906.990 us; speedup vs baseline: 1.0736x; 1.0736x over previous
//
#include <hip/hip_runtime.h>

#define TT 512
#define BB 64
#define II 128
#define HH 1024
#define OO 128
#define NWG 196

typedef _Float16 half8 __attribute__((ext_vector_type(8)));
typedef float floatx4 __attribute__((ext_vector_type(4)));
typedef unsigned long long u64;

__device__ unsigned g_bar_cnt;   // reset by prep_x each call (agent-scope store)

__device__ __forceinline__ float sigm(float x){ return 1.0f/(1.0f + __expf(-x)); }

union H8cv { u64 u[2]; half8 h; };

// agent-scope (cross-XCD coherent, LLC-direct) h-fragment load
__device__ __forceinline__ half8 ld_h8_dev(const _Float16* p){
  H8cv cv;
  cv.u[0] = __hip_atomic_load((const u64*)p + 0, __ATOMIC_RELAXED, __HIP_MEMORY_SCOPE_AGENT);
  cv.u[1] = __hip_atomic_load((const u64*)p + 1, __ATOMIC_RELAXED, __HIP_MEMORY_SCOPE_AGENT);
  return cv.h;
}

// Pack adjacent-column pair into one 32-bit agent-scope store (even lane stores).
// Lanes n and n^1 hold adjacent columns of the same row.
__device__ __forceinline__ void st_h_pair(_Float16* rowbase, int col, float v, int lane){
  unsigned mv = (unsigned)__builtin_bit_cast(unsigned short, (_Float16)v);
  unsigned pv = ((unsigned)__shfl_xor((int)mv, 1, 64)) & 0xffffu;
  if (!(lane & 1)){
    unsigned word = (pv << 16) | mv;
    __hip_atomic_store((unsigned*)(rowbase + col), word,
                       __ATOMIC_RELAXED, __HIP_MEMORY_SCOPE_AGENT);
  }
}

// Monotonic grid barrier, FULLY RELAXED arrivals.
// Correctness: h stores are agent-scope (sc1) -> ACKed at the LLC coherence
// point; vmcnt(0) drain before arrival means h data is physically at LLC
// before the counter bump. No release needed -> no buffer_wbl2 L2 tag-walk
// (R7's 43 us/interval). Weights stay clean-resident in per-XCD L2.
__device__ __forceinline__ void fastbar(unsigned target){
  asm volatile("s_waitcnt vmcnt(0)" ::: "memory");
  __syncthreads();
  if (threadIdx.x == 0){
    __hip_atomic_fetch_add(&g_bar_cnt, 1u, __ATOMIC_RELAXED, __HIP_MEMORY_SCOPE_AGENT);
    while (__hip_atomic_load(&g_bar_cnt, __ATOMIC_RELAXED, __HIP_MEMORY_SCOPE_AGENT) < target)
      __builtin_amdgcn_s_sleep(1);
  }
  __syncthreads();
}

// ---------------- prep kernels ----------------
__global__ void prep_x_kernel(const float* __restrict__ x, _Float16* __restrict__ X16){
  if (blockIdx.x == 0 && threadIdx.x == 0)
    __hip_atomic_store(&g_bar_cnt, 0u, __ATOMIC_RELAXED, __HIP_MEMORY_SCOPE_AGENT);
  int idx = blockIdx.x*256 + threadIdx.x;         // idx over [t][b][i]
  int i = idx & (II-1);
  int b = (idx >> 7) & (BB-1);
  int t = idx >> 13;
  X16[idx] = (_Float16)x[((size_t)b*TT + t)*II + i];
}

__global__ void prep_w_kernel(const float* __restrict__ wih1, const float* __restrict__ whh1,
                              const float* __restrict__ wih2, const float* __restrict__ whh2,
                              const float* __restrict__ wlin,
                              _Float16* __restrict__ W1, _Float16* __restrict__ W2,
                              _Float16* __restrict__ WL, _Float16* __restrict__ H1,
                              _Float16* __restrict__ H2){
  long idx = (long)blockIdx.x*256 + threadIdx.x;
  const long n1 = 4096L*1152, n2 = 4096L*2048, nl = 128L*1024;
  if (idx < n1){
    int k = (int)(idx % 1152); int j = (int)(idx / 1152);
    W1[idx] = (_Float16)(k < II ? wih1[(size_t)j*II + k] : whh1[(size_t)j*HH + (k-II)]);
  } else if ((idx -= n1) < n2){
    int k = (int)(idx % 2048); int j = (int)(idx / 2048);
    W2[idx] = (_Float16)(k < HH ? wih2[(size_t)j*HH + k] : whh2[(size_t)j*HH + (k-HH)]);
  } else if ((idx -= n2) < nl){
    WL[idx] = (_Float16)wlin[idx];
  } else {
    idx -= nl;                                    // [0, 2*BB*HH)
    H1[idx] = (_Float16)0.0f;
    H2[idx] = (_Float16)0.0f;
  }
}

// ---------------- persistent pipelined LSTM (NORMAL launch) ----------------
// 196 WGs x 256 thr, plain <<<>>> launch (hipLaunchCooperativeKernel silently
// rejected earlier variants). 196 blocks on 256 CUs -> co-resident (proven R7).
//   wg   0..63 : layer-1, 16 units (64x64 gate tile, K=1152)
//   wg  64..191: layer-2,  8 units (64x32 gate tile, K=2048)
//   wg 192..195: output projection, 32 cols (64x32, K=1024)
// Interval s: L1 t=s, L2 t=s-1, Y t=s-2; fastbar between intervals.
__global__ void __launch_bounds__(256, 1)
lstm_persist_kernel(const _Float16* __restrict__ X16,
                    const _Float16* __restrict__ W1,
                    const _Float16* __restrict__ W2,
                    const _Float16* __restrict__ WL,
                    _Float16* __restrict__ H1,
                    _Float16* __restrict__ H2,
                    const float* __restrict__ bi1, const float* __restrict__ bh1,
                    const float* __restrict__ bi2, const float* __restrict__ bh2,
                    const float* __restrict__ blin,
                    float* __restrict__ out)
{
  const int wg   = blockIdx.x;
  const int tid  = threadIdx.x;
  const int wv   = tid >> 6;
  const int lane = tid & 63;
  const int q    = lane >> 4;
  const int n    = lane & 15;
  const int mrow = wv << 4;
  const floatx4 zero4 = {0.f, 0.f, 0.f, 0.f};

  if (wg < 64){
    // ---------------- layer 1 ----------------
    const int j0 = wg << 4;
    const int j  = j0 + n;
    const _Float16* wrow[4];
    float bias[4];
#pragma unroll
    for (int g = 0; g < 4; ++g){
      wrow[g] = W1 + (size_t)(g*HH + j)*1152 + q*8;
      bias[g] = bi1[g*HH + j] + bh1[g*HH + j];
    }
    // x-part weights: registers for all 512 steps
    half8 Wx[4][4];
#pragma unroll
    for (int g = 0; g < 4; ++g)
#pragma unroll
      for (int c = 0; c < 4; ++c)
        Wx[g][c] = *(const half8*)(wrow[g] + c*32);

    float c1s[4] = {0.f, 0.f, 0.f, 0.f};
    for (int s = 0; s < TT + 2; ++s){
      if (s < TT){
        const int t = s;
        const _Float16* xb = X16 + ((size_t)t*BB + (mrow+n))*II + q*8;
        const _Float16* hb = H1 + ((size_t)((t+1)&1)*BB + (mrow+n))*HH + q*8;
        half8 xf[4];
#pragma unroll
        for (int c = 0; c < 4; ++c) xf[c] = *(const half8*)(xb + c*32);
        half8 hA[32];
#pragma unroll
        for (int c = 0; c < 32; ++c) hA[c] = ld_h8_dev(hb + c*32);

        floatx4 acc[4];
#pragma unroll
        for (int g = 0; g < 4; ++g) acc[g] = zero4;
#pragma unroll
        for (int c = 0; c < 4; ++c)
#pragma unroll
          for (int g = 0; g < 4; ++g)
            acc[g] = __builtin_amdgcn_mfma_f32_16x16x32_f16(xf[c], Wx[g][c], acc[g], 0, 0, 0);
#pragma unroll
        for (int g = 0; g < 4; ++g){
          half8 Wb[32];
#pragma unroll
          for (int c = 0; c < 32; ++c) Wb[c] = *(const half8*)(wrow[g] + (4+c)*32);
#pragma unroll
          for (int c = 0; c < 32; ++c)
            acc[g] = __builtin_amdgcn_mfma_f32_16x16x32_f16(hA[c], Wb[c], acc[g], 0, 0, 0);
        }
        _Float16* ho = H1 + (size_t)(t&1)*BB*HH;
#pragma unroll
        for (int r = 0; r < 4; ++r){
          float gi = acc[0][r] + bias[0];
          float gf = acc[1][r] + bias[1];
          float gg = acc[2][r] + bias[2];
          float go = acc[3][r] + bias[3];
          float cc = sigm(gf)*c1s[r] + sigm(gi)*tanhf(gg);
          c1s[r] = cc;
          float h = sigm(go)*tanhf(cc);
          st_h_pair(ho + (size_t)(mrow + q*4 + r)*HH, j, h, lane);
        }
      }
      fastbar(NWG*(unsigned)(s+1));
    }
  } else if (wg < 192){
    // ---------------- layer 2 ----------------
    const int j0 = (wg - 64) << 3;
    const int jj = j0 + (n & 7);
    const _Float16* wrow[2];
#pragma unroll
    for (int p = 0; p < 2; ++p)
      wrow[p] = W2 + (size_t)((p*2 + (n>>3))*HH + jj)*2048 + q*8;
    float bias[4];
#pragma unroll
    for (int g = 0; g < 4; ++g) bias[g] = bi2[g*HH + jj] + bh2[g*HH + jj];
    float c2s[2] = {0.f, 0.f};
    const int rbase = (n < 8) ? 0 : 2;
    for (int s = 0; s < TT + 2; ++s){
      if (s >= 1 && s <= TT){
        const int t = s - 1;
        const _Float16* a1 = H1 + ((size_t)(t&1)*BB + (mrow+n))*HH + q*8;
        const _Float16* a2 = H2 + ((size_t)((t+1)&1)*BB + (mrow+n))*HH + q*8;
        half8 hA1[32];
#pragma unroll
        for (int c = 0; c < 32; ++c) hA1[c] = ld_h8_dev(a1 + c*32);
        half8 hA2[32];
#pragma unroll
        for (int c = 0; c < 32; ++c) hA2[c] = ld_h8_dev(a2 + c*32);

        floatx4 acc[2];
        acc[0] = zero4; acc[1] = zero4;
#pragma unroll
        for (int p = 0; p < 2; ++p){
          half8 Wb[32];
#pragma unroll
          for (int c = 0; c < 32; ++c) Wb[c] = *(const half8*)(wrow[p] + c*32);
#pragma unroll
          for (int c = 0; c < 32; ++c)
            acc[p] = __builtin_amdgcn_mfma_f32_16x16x32_f16(hA1[c], Wb[c], acc[p], 0, 0, 0);
#pragma unroll
          for (int c = 0; c < 32; ++c) Wb[c] = *(const half8*)(wrow[p] + (32+c)*32);
#pragma unroll
          for (int c = 0; c < 32; ++c)
            acc[p] = __builtin_amdgcn_mfma_f32_16x16x32_f16(hA2[c], Wb[c], acc[p], 0, 0, 0);
        }
        float vi[4], vf[4], vg[4], vo[4];
#pragma unroll
        for (int r = 0; r < 4; ++r){
          float p0 = acc[0][r], p1 = acc[1][r];
          float s0 = __shfl_xor(p0, 8, 64);
          float s1 = __shfl_xor(p1, 8, 64);
          vi[r] = (n < 8) ? p0 : s0;
          vf[r] = (n < 8) ? s0 : p0;
          vg[r] = (n < 8) ? p1 : s1;
          vo[r] = (n < 8) ? s1 : p1;
        }
        _Float16* ho = H2 + (size_t)(t&1)*BB*HH;
#pragma unroll
        for (int rr = 0; rr < 2; ++rr){
          int r = rbase + rr;
          float gi = vi[r] + bias[0];
          float gf = vf[r] + bias[1];
          float gg = vg[r] + bias[2];
          float go = vo[r] + bias[3];
          float cc = sigm(gf)*c2s[rr] + sigm(gi)*tanhf(gg);
          c2s[rr] = cc;
          float h = sigm(go)*tanhf(cc);
          st_h_pair(ho + (size_t)(mrow + q*4 + r)*HH, jj, h, lane);
        }
      }
      fastbar(NWG*(unsigned)(s+1));
    }
  } else {
    // ---------------- output projection ----------------
    const int j0 = (wg - 192) << 5;
    const _Float16* wrow[2];
    float by[2];
#pragma unroll
    for (int p = 0; p < 2; ++p){
      wrow[p] = WL + (size_t)(j0 + p*16 + n)*HH + q*8;
      by[p] = blin[j0 + p*16 + n];
    }
    for (int s = 0; s < TT + 2; ++s){
      if (s >= 2){
        const int t = s - 2;
        const _Float16* a2 = H2 + ((size_t)(t&1)*BB + (mrow+n))*HH + q*8;
        half8 hA[32];
#pragma unroll
        for (int c = 0; c < 32; ++c) hA[c] = ld_h8_dev(a2 + c*32);
        floatx4 acc[2];
        acc[0] = zero4; acc[1] = zero4;
#pragma unroll
        for (int p = 0; p < 2; ++p){
          half8 Wb[32];
#pragma unroll
          for (int c = 0; c < 32; ++c) Wb[c] = *(const half8*)(wrow[p] + c*32);
#pragma unroll
          for (int c = 0; c < 32; ++c)
            acc[p] = __builtin_amdgcn_mfma_f32_16x16x32_f16(hA[c], Wb[c], acc[p], 0, 0, 0);
        }
#pragma unroll
        for (int p = 0; p < 2; ++p){
          int col = j0 + p*16 + n;
#pragma unroll
          for (int r = 0; r < 4; ++r){
            int b = mrow + q*4 + r;
            out[((size_t)b*TT + t)*OO + col] = acc[p][r] + by[p];
          }
        }
      }
      fastbar(NWG*(unsigned)(s+1));
    }
  }
}

// ---------------- launch ----------------
extern "C" void kernel_launch(void* const* d_in, const int* in_sizes, int n_in,
                              void* d_out, int out_size, void* d_ws, size_t ws_size,
                              hipStream_t stream){
  const float* x    = (const float*)d_in[0];
  const float* wih1 = (const float*)d_in[1];
  const float* whh1 = (const float*)d_in[2];
  const float* bi1  = (const float*)d_in[3];
  const float* bh1  = (const float*)d_in[4];
  const float* wih2 = (const float*)d_in[5];
  const float* whh2 = (const float*)d_in[6];
  const float* bi2  = (const float*)d_in[7];
  const float* bh2  = (const float*)d_in[8];
  const float* wlin = (const float*)d_in[9];
  const float* blin = (const float*)d_in[10];
  float* out = (float*)d_out;

  char* ws = (char*)d_ws;
  _Float16* X16 = (_Float16*)(ws + 0);          //  8,388,608  [512][64][128]
  _Float16* W1  = (_Float16*)(ws + 8388608);    //  9,437,184  [4096][1152]
  _Float16* W2  = (_Float16*)(ws + 17825792);   // 16,777,216  [4096][2048]
  _Float16* WL  = (_Float16*)(ws + 34603008);   //    262,144  [128][1024]
  _Float16* H1  = (_Float16*)(ws + 34865152);   //    262,144  [2][64][1024]
  _Float16* H2  = (_Float16*)(ws + 35127296);   //    262,144  [2][64][1024]

  prep_x_kernel<<<dim3(16384), dim3(256), 0, stream>>>(x, X16);
  prep_w_kernel<<<dim3(52224), dim3(256), 0, stream>>>(wih1, whh1, wih2, whh2, wlin,
                                                       W1, W2, WL, H1, H2);

  lstm_persist_kernel<<<dim3(NWG), dim3(256), 0, stream>>>(
      X16, W1, W2, WL, H1, H2, bi1, bh1, bi2, bh2, blin, out);
}

// Round 10
// 20578.725 us; speedup vs baseline: 1.1429x; 1.0645x over previous
//
#include <hip/hip_runtime.h>

#define TT 512
#define BB 64
#define II 128
#define HH 1024
#define OO 128
#define NWG 196
#define SYNC_STRIDE 64   // 256 B between counters -> distinct LLC lines/banks

typedef _Float16 half8 __attribute__((ext_vector_type(8)));
typedef float floatx4 __attribute__((ext_vector_type(4)));
typedef unsigned long long u64;

// 0..7: per-group arrival counters; 8: master; 9..16: per-group go flags
__device__ unsigned g_sync[17*SYNC_STRIDE];

__device__ __forceinline__ float sigm(float x){ return 1.0f/(1.0f + __expf(-x)); }

union H8cv { u64 u[2]; half8 h; };

// agent-scope (cross-XCD coherent, LLC-direct) h-fragment load — proven R8 path
__device__ __forceinline__ half8 ld_h8_dev(const _Float16* p){
  H8cv cv;
  cv.u[0] = __hip_atomic_load((const u64*)p + 0, __ATOMIC_RELAXED, __HIP_MEMORY_SCOPE_AGENT);
  cv.u[1] = __hip_atomic_load((const u64*)p + 1, __ATOMIC_RELAXED, __HIP_MEMORY_SCOPE_AGENT);
  return cv.h;
}

// Pack adjacent-column pair into one 32-bit agent-scope store (even lane stores).
__device__ __forceinline__ void st_h_pair(_Float16* rowbase, int col, float v, int lane){
  unsigned mv = (unsigned)__builtin_bit_cast(unsigned short, (_Float16)v);
  unsigned pv = ((unsigned)__shfl_xor((int)mv, 1, 64)) & 0xffffu;
  if (!(lane & 1)){
    unsigned word = (pv << 16) | mv;
    __hip_atomic_store((unsigned*)(rowbase + col), word,
                       __ATOMIC_RELAXED, __HIP_MEMORY_SCOPE_AGENT);
  }
}

__device__ __forceinline__ unsigned ld_sync(const unsigned* p){
  return __hip_atomic_load(p, __ATOMIC_RELAXED, __HIP_MEMORY_SCOPE_AGENT);
}

// Hierarchical monotonic grid barrier (anti poll-storm).
// R8's single-line barrier: 196 spinners hammer one LLC line at ~0.7us period;
// polls serialize at the line's bank and arrivals queue behind them (~30us).
// Here: 8 arrival lines (24-25 RMWs each), 1 master line (8 RMWs, 8 slow
// spinners), 8 go lines (~24 spinners each, s_sleep(16) ~ 1.6K cyc period).
// All relaxed agent-scope; h stores are LLC-ACKed and vmcnt(0)-drained before
// arrival, so no release/acquire cache maintenance; weights stay L2-resident.
__device__ __forceinline__ void fastbar(int wg, unsigned step1){
  asm volatile("s_waitcnt vmcnt(0)" ::: "memory");
  __syncthreads();
  if (threadIdx.x == 0){
    const int g = wg & 7;
    unsigned* arrive = &g_sync[g*SYNC_STRIDE];
    unsigned* master = &g_sync[8*SYNC_STRIDE];
    unsigned* go     = &g_sync[(9+g)*SYNC_STRIDE];
    __hip_atomic_fetch_add(arrive, 1u, __ATOMIC_RELAXED, __HIP_MEMORY_SCOPE_AGENT);
    if (wg < 8){
      const unsigned cntg = (g < (NWG & 7)) ? (NWG/8 + 1) : (NWG/8);
      while (ld_sync(arrive) < cntg*step1) __builtin_amdgcn_s_sleep(8);
      __hip_atomic_fetch_add(master, 1u, __ATOMIC_RELAXED, __HIP_MEMORY_SCOPE_AGENT);
      while (ld_sync(master) < 8u*step1) __builtin_amdgcn_s_sleep(8);
      __hip_atomic_store(go, step1, __ATOMIC_RELAXED, __HIP_MEMORY_SCOPE_AGENT);
    } else {
      while (ld_sync(go) < step1) __builtin_amdgcn_s_sleep(16);
    }
  }
  __syncthreads();
}

// ---------------- prep kernels ----------------
__global__ void prep_x_kernel(const float* __restrict__ x, _Float16* __restrict__ X16){
  int idx = blockIdx.x*256 + threadIdx.x;         // idx over [t][b][i]
  if (idx < 17*SYNC_STRIDE) g_sync[idx] = 0u;     // kernel-boundary release publishes
  int i = idx & (II-1);
  int b = (idx >> 7) & (BB-1);
  int t = idx >> 13;
  X16[idx] = (_Float16)x[((size_t)b*TT + t)*II + i];
}

__global__ void prep_w_kernel(const float* __restrict__ wih1, const float* __restrict__ whh1,
                              const float* __restrict__ wih2, const float* __restrict__ whh2,
                              const float* __restrict__ wlin,
                              _Float16* __restrict__ W1, _Float16* __restrict__ W2,
                              _Float16* __restrict__ WL, _Float16* __restrict__ H1,
                              _Float16* __restrict__ H2){
  long idx = (long)blockIdx.x*256 + threadIdx.x;
  const long n1 = 4096L*1152, n2 = 4096L*2048, nl = 128L*1024;
  if (idx < n1){
    int k = (int)(idx % 1152); int j = (int)(idx / 1152);
    W1[idx] = (_Float16)(k < II ? wih1[(size_t)j*II + k] : whh1[(size_t)j*HH + (k-II)]);
  } else if ((idx -= n1) < n2){
    int k = (int)(idx % 2048); int j = (int)(idx / 2048);
    W2[idx] = (_Float16)(k < HH ? wih2[(size_t)j*HH + k] : whh2[(size_t)j*HH + (k-HH)]);
  } else if ((idx -= n2) < nl){
    WL[idx] = (_Float16)wlin[idx];
  } else {
    idx -= nl;                                    // [0, 2*BB*HH)
    H1[idx] = (_Float16)0.0f;
    H2[idx] = (_Float16)0.0f;
  }
}

// ---------------- persistent pipelined LSTM (NORMAL launch) ----------------
// 196 WGs x 256 thr, plain <<<>>> launch. 196 blocks on 256 CUs -> co-resident.
//   wg   0..63 : layer-1, 16 units (64x64 gate tile, K=1152)
//   wg  64..191: layer-2,  8 units (64x32 gate tile, K=2048)
//   wg 192..195: output projection, 32 cols (64x32, K=1024)
// Interval s: L1 t=s, L2 t=s-1, Y t=s-2; fastbar between intervals.
__global__ void __launch_bounds__(256, 1)
lstm_persist_kernel(const _Float16* __restrict__ X16,
                    const _Float16* __restrict__ W1,
                    const _Float16* __restrict__ W2,
                    const _Float16* __restrict__ WL,
                    _Float16* __restrict__ H1,
                    _Float16* __restrict__ H2,
                    const float* __restrict__ bi1, const float* __restrict__ bh1,
                    const float* __restrict__ bi2, const float* __restrict__ bh2,
                    const float* __restrict__ blin,
                    float* __restrict__ out)
{
  const int wg   = blockIdx.x;
  const int tid  = threadIdx.x;
  const int wv   = tid >> 6;
  const int lane = tid & 63;
  const int q    = lane >> 4;
  const int n    = lane & 15;
  const int mrow = wv << 4;
  const floatx4 zero4 = {0.f, 0.f, 0.f, 0.f};

  if (wg < 64){
    // ---------------- layer 1 ----------------
    const int j0 = wg << 4;
    const int j  = j0 + n;
    const _Float16* wrow[4];
    float bias[4];
#pragma unroll
    for (int g = 0; g < 4; ++g){
      wrow[g] = W1 + (size_t)(g*HH + j)*1152 + q*8;
      bias[g] = bi1[g*HH + j] + bh1[g*HH + j];
    }
    // x-part weights: registers for all 512 steps
    half8 Wx[4][4];
#pragma unroll
    for (int g = 0; g < 4; ++g)
#pragma unroll
      for (int c = 0; c < 4; ++c)
        Wx[g][c] = *(const half8*)(wrow[g] + c*32);

    float c1s[4] = {0.f, 0.f, 0.f, 0.f};
    for (int s = 0; s < TT + 2; ++s){
      if (s < TT){
        const int t = s;
        const _Float16* xb = X16 + ((size_t)t*BB + (mrow+n))*II + q*8;
        const _Float16* hb = H1 + ((size_t)((t+1)&1)*BB + (mrow+n))*HH + q*8;
        half8 xf[4];
#pragma unroll
        for (int c = 0; c < 4; ++c) xf[c] = *(const half8*)(xb + c*32);
        half8 hA[32];
#pragma unroll
        for (int c = 0; c < 32; ++c) hA[c] = ld_h8_dev(hb + c*32);

        floatx4 acc[4];
#pragma unroll
        for (int g = 0; g < 4; ++g) acc[g] = zero4;
#pragma unroll
        for (int c = 0; c < 4; ++c)
#pragma unroll
          for (int g = 0; g < 4; ++g)
            acc[g] = __builtin_amdgcn_mfma_f32_16x16x32_f16(xf[c], Wx[g][c], acc[g], 0, 0, 0);
#pragma unroll
        for (int g = 0; g < 4; ++g){
          half8 Wb[32];
#pragma unroll
          for (int c = 0; c < 32; ++c) Wb[c] = *(const half8*)(wrow[g] + (4+c)*32);
#pragma unroll
          for (int c = 0; c < 32; ++c)
            acc[g] = __builtin_amdgcn_mfma_f32_16x16x32_f16(hA[c], Wb[c], acc[g], 0, 0, 0);
        }
        _Float16* ho = H1 + (size_t)(t&1)*BB*HH;
#pragma unroll
        for (int r = 0; r < 4; ++r){
          float gi = acc[0][r] + bias[0];
          float gf = acc[1][r] + bias[1];
          float gg = acc[2][r] + bias[2];
          float go = acc[3][r] + bias[3];
          float cc = sigm(gf)*c1s[r] + sigm(gi)*tanhf(gg);
          c1s[r] = cc;
          float h = sigm(go)*tanhf(cc);
          st_h_pair(ho + (size_t)(mrow + q*4 + r)*HH, j, h, lane);
        }
      }
      fastbar(wg, (unsigned)(s+1));
    }
  } else if (wg < 192){
    // ---------------- layer 2 ----------------
    const int j0 = (wg - 64) << 3;
    const int jj = j0 + (n & 7);
    const _Float16* wrow[2];
#pragma unroll
    for (int p = 0; p < 2; ++p)
      wrow[p] = W2 + (size_t)((p*2 + (n>>3))*HH + jj)*2048 + q*8;
    float bias[4];
#pragma unroll
    for (int g = 0; g < 4; ++g) bias[g] = bi2[g*HH + jj] + bh2[g*HH + jj];
    float c2s[2] = {0.f, 0.f};
    const int rbase = (n < 8) ? 0 : 2;
    for (int s = 0; s < TT + 2; ++s){
      if (s >= 1 && s <= TT){
        const int t = s - 1;
        const _Float16* a1 = H1 + ((size_t)(t&1)*BB + (mrow+n))*HH + q*8;
        const _Float16* a2 = H2 + ((size_t)((t+1)&1)*BB + (mrow+n))*HH + q*8;
        half8 hA1[32];
#pragma unroll
        for (int c = 0; c < 32; ++c) hA1[c] = ld_h8_dev(a1 + c*32);
        half8 hA2[32];
#pragma unroll
        for (int c = 0; c < 32; ++c) hA2[c] = ld_h8_dev(a2 + c*32);

        floatx4 acc[2];
        acc[0] = zero4; acc[1] = zero4;
#pragma unroll
        for (int p = 0; p < 2; ++p){
          half8 Wb[32];
#pragma unroll
          for (int c = 0; c < 32; ++c) Wb[c] = *(const half8*)(wrow[p] + c*32);
#pragma unroll
          for (int c = 0; c < 32; ++c)
            acc[p] = __builtin_amdgcn_mfma_f32_16x16x32_f16(hA1[c], Wb[c], acc[p], 0, 0, 0);
#pragma unroll
          for (int c = 0; c < 32; ++c) Wb[c] = *(const half8*)(wrow[p] + (32+c)*32);
#pragma unroll
          for (int c = 0; c < 32; ++c)
            acc[p] = __builtin_amdgcn_mfma_f32_16x16x32_f16(hA2[c], Wb[c], acc[p], 0, 0, 0);
        }
        float vi[4], vf[4], vg[4], vo[4];
#pragma unroll
        for (int r = 0; r < 4; ++r){
          float p0 = acc[0][r], p1 = acc[1][r];
          float s0 = __shfl_xor(p0, 8, 64);
          float s1 = __shfl_xor(p1, 8, 64);
          vi[r] = (n < 8) ? p0 : s0;
          vf[r] = (n < 8) ? s0 : p0;
          vg[r] = (n < 8) ? p1 : s1;
          vo[r] = (n < 8) ? s1 : p1;
        }
        _Float16* ho = H2 + (size_t)(t&1)*BB*HH;
#pragma unroll
        for (int rr = 0; rr < 2; ++rr){
          int r = rbase + rr;
          float gi = vi[r] + bias[0];
          float gf = vf[r] + bias[1];
          float gg = vg[r] + bias[2];
          float go = vo[r] + bias[3];
          float cc = sigm(gf)*c2s[rr] + sigm(gi)*tanhf(gg);
          c2s[rr] = cc;
          float h = sigm(go)*tanhf(cc);
          st_h_pair(ho + (size_t)(mrow + q*4 + r)*HH, jj, h, lane);
        }
      }
      fastbar(wg, (unsigned)(s+1));
    }
  } else {
    // ---------------- output projection ----------------
    const int j0 = (wg - 192) << 5;
    const _Float16* wrow[2];
    float by[2];
#pragma unroll
    for (int p = 0; p < 2; ++p){
      wrow[p] = WL + (size_t)(j0 + p*16 + n)*HH + q*8;
      by[p] = blin[j0 + p*16 + n];
    }
    for (int s = 0; s < TT + 2; ++s){
      if (s >= 2){
        const int t = s - 2;
        const _Float16* a2 = H2 + ((size_t)(t&1)*BB + (mrow+n))*HH + q*8;
        half8 hA[32];
#pragma unroll
        for (int c = 0; c < 32; ++c) hA[c] = ld_h8_dev(a2 + c*32);
        floatx4 acc[2];
        acc[0] = zero4; acc[1] = zero4;
#pragma unroll
        for (int p = 0; p < 2; ++p){
          half8 Wb[32];
#pragma unroll
          for (int c = 0; c < 32; ++c) Wb[c] = *(const half8*)(wrow[p] + c*32);
#pragma unroll
          for (int c = 0; c < 32; ++c)
            acc[p] = __builtin_amdgcn_mfma_f32_16x16x32_f16(hA[c], Wb[c], acc[p], 0, 0, 0);
        }
#pragma unroll
        for (int p = 0; p < 2; ++p){
          int col = j0 + p*16 + n;
#pragma unroll
          for (int r = 0; r < 4; ++r){
            int b = mrow + q*4 + r;
            out[((size_t)b*TT + t)*OO + col] = acc[p][r] + by[p];
          }
        }
      }
      fastbar(wg, (unsigned)(s+1));
    }
  }
}

// ---------------- launch ----------------
extern "C" void kernel_launch(void* const* d_in, const int* in_sizes, int n_in,
                              void* d_out, int out_size, void* d_ws, size_t ws_size,
                              hipStream_t stream){
  const float* x    = (const float*)d_in[0];
  const float* wih1 = (const float*)d_in[1];
  const float* whh1 = (const float*)d_in[2];
  const float* bi1  = (const float*)d_in[3];
  const float* bh1  = (const float*)d_in[4];
  const float* wih2 = (const float*)d_in[5];
  const float* whh2 = (const float*)d_in[6];
  const float* bi2  = (const float*)d_in[7];
  const float* bh2  = (const float*)d_in[8];
  const float* wlin = (const float*)d_in[9];
  const float* blin = (const float*)d_in[10];
  float* out = (float*)d_out;

  char* ws = (char*)d_ws;
  _Float16* X16 = (_Float16*)(ws + 0);          //  8,388,608  [512][64][128]
  _Float16* W1  = (_Float16*)(ws + 8388608);    //  9,437,184  [4096][1152]
  _Float16* W2  = (_Float16*)(ws + 17825792);   // 16,777,216  [4096][2048]
  _Float16* WL  = (_Float16*)(ws + 34603008);   //    262,144  [128][1024]
  _Float16* H1  = (_Float16*)(ws + 34865152);   //    262,144  [2][64][1024]
  _Float16* H2  = (_Float16*)(ws + 35127296);   //    262,144  [2][64][1024]

  prep_x_kernel<<<dim3(16384), dim3(256), 0, stream>>>(x, X16);
  prep_w_kernel<<<dim3(52224), dim3(256), 0, stream>>>(wih1, whh1, wih2, whh2, wlin,
                                                       W1, W2, WL, H1, H2);

  lstm_persist_kernel<<<dim3(NWG), dim3(256), 0, stream>>>(
      X16, W1, W2, WL, H1, H2, bi1, bh1, bi2, bh2, blin, out);
}